// Round 5
// 1325.793 us; speedup vs baseline: 1.1868x; 1.1868x over previous
//
#include <hip/hip_runtime.h>

// ManyChannelsIntegrator: C=2, B=256, T=256, N=2048
// R15: 8x32 XCD-friendly geometry, ONLY round-0-proven constructs.
//  - 8 groups x 32 blocks; group g = blk&7 (XCD if m09 mapping holds - but
//    correctness does NOT depend on it: all exchange is system-scope).
//  - Each block: rows g*32..+32, cols bnx*64..+64.
//  - W tile (64 cols x 2048 k bf16) in registers (32 x s16x8 per wave).
//  - 8 waves = 8 k-eighths; A (S strip) read via plain cached loads,
//    register ring + counted vmcnt (round-0 idiom). L2 dedups the 32-way
//    broadcast within each XCD automatically.
//  - S exchange: sc0 sc1 write-through stores (never dirty L2) + plain reads
//    + NSB=8 rotation with agent-acquire inv every 8 steps: each slot's
//    consecutive reads straddle exactly one inv boundary (round-0 proven).
//  - Flags: __hip_atomic_store/load SYSTEM scope (round-0 proven), 32 members.

#define NN 2048
#define BB 256
#define TT 256
#define SLOPE 8.0f

#define NBLK 256
#define NTH  512
#define NSB  8      // S rotation depth; inv every NSB steps

// ---- LDS layout (bytes) ----
#define MRGS 68                            // merge region stride (f32 words)
#define RSZW (32*MRGS)                     // words per region (2176)
#define LDS_R0    0                        // 4 regions x 8704 B = 34816
#define LDS_CONST (4*RSZW*4)               // 7 x 64 f32 per-n constants
#define LDS_TOTAL (LDS_CONST + 7*64*4)     // 36608 B

// ---- ws layout (bytes) ----
#define WS_FLAGS 0                         // [8 g][32 member] x 128 B (memset 0)
#define WS_SBUF  32768                     // 8 groups x NSB x 128 KB = 8 MB
#define SBUF_SZ  131072
#define WS_PART  (32768 + 8*NSB*SBUF_SZ)   // [T][32 bn][256 b] u32

typedef short s16x8 __attribute__((ext_vector_type(8)));      // 8 bf16
typedef float f32x16 __attribute__((ext_vector_type(16)));
typedef unsigned u32x4 __attribute__((ext_vector_type(4)));
typedef unsigned u32x2 __attribute__((ext_vector_type(2)));

__device__ __forceinline__ unsigned f2bf1(float f) {
  union { float f; unsigned u; } v; v.f = f;
  return (v.u + 0x7fffu + ((v.u >> 16) & 1u)) >> 16;   // RNE
}
__device__ __forceinline__ unsigned pack2(float a, float b) {
  return f2bf1(a) | (f2bf1(b) << 16);
}

// System-scope write-through stores (never dirty L1/L2 -> buffer_inv safe).
__device__ __forceinline__ void store_b64_sys(void* p, u32x2 v) {
  asm volatile("global_store_dwordx2 %0, %1, off sc0 sc1" :: "v"(p), "v"(v) : "memory");
}
__device__ __forceinline__ void store_u32_sys(void* p, unsigned v) {
  asm volatile("global_store_dword %0, %1, off sc0 sc1" :: "v"(p), "v"(v) : "memory");
}

// A-load: plain -> L1/L2-cached (round-0 proven: L2 dedups the broadcast).
#define LOAD_A(dst, base, OFF) \
  asm volatile("global_load_dwordx4 %0, %1, off offset:" #OFF \
               : "=v"(dst) : "v"(base) : "memory")

// Group barrier over 32 members (round-0 shape, line-padded flags):
//  drain stores -> block sync -> ONE flag store (own line) ->
//  poll 32 member lines -> sync. Optional agent-acquire fence (inv cadence).
__device__ __forceinline__ void grid_barrier(unsigned* flags, int gbase, int member,
                                             unsigned tval, bool do_inv) {
  asm volatile("s_waitcnt vmcnt(0)" ::: "memory");
  __syncthreads();
  const int tid = threadIdx.x;
  if (tid == 0)
    __hip_atomic_store(&flags[(gbase + member) * 32], tval,
                       __ATOMIC_RELAXED, __HIP_MEMORY_SCOPE_SYSTEM);
  if (tid < 64) {
    for (;;) {
      unsigned v = __hip_atomic_load(&flags[(gbase + (tid & 31)) * 32],
                                     __ATOMIC_RELAXED, __HIP_MEMORY_SCOPE_SYSTEM);
      if (__all(v >= tval)) break;
      __builtin_amdgcn_s_sleep(1);
    }
  }
  __syncthreads();
  if (do_inv) {
    if (tid < 64) __builtin_amdgcn_fence(__ATOMIC_ACQUIRE, "agent");
    __syncthreads();
  }
}

__global__ __launch_bounds__(NTH, 2)
void mc_integrator_kernel(const float* __restrict__ x, const float* __restrict__ state0,
                          const float* __restrict__ mask, const float* __restrict__ enc,
                          const float* __restrict__ dec, const float* __restrict__ W,
                          const float* __restrict__ bias, const float* __restrict__ thr,
                          char* __restrict__ ws)
{
  extern __shared__ char lds[];
  const int tid = threadIdx.x;
  const int blk = blockIdx.x;
  const int g   = blk & 7;          // group (XCD under m09 round-robin)
  const int bnx = blk >> 3;         // 0..31: 64-col n-strip
  const int C0  = bnx * 64;
  const int kq  = tid >> 6;         // wave = k-eighth (256 k)
  const int lane = tid & 63;

  unsigned* flags = (unsigned*)(ws + WS_FLAGS);   // member stride = 128 B
  char* sbufs = ws + WS_SBUF;
  unsigned* partials = (unsigned*)(ws + WS_PART);

  // ---- stage per-n constants (64 cols) ----
  float* cmask = (float*)(lds + LDS_CONST);
  float* cbias = cmask + 64; float* cthr  = cbias + 64;
  float* cenc0 = cthr  + 64; float* cenc1 = cenc0 + 64;
  float* cdec0 = cenc1 + 64; float* cdec1 = cdec0 + 64;
  if (tid < 64) {
    int n = C0 + tid;
    cmask[tid] = mask[n]; cbias[tid] = bias[n]; cthr[tid] = thr[n];
    cenc0[tid] = enc[n];  cenc1[tid] = enc[NN + n];
    cdec0[tid] = dec[n];  cdec1[tid] = dec[NN + n];
  }

  // ---- W -> registers. Wave kq owns k [kq*256,+256), all 64 cols.
  // Breg[j*2+h]: k-chunk j (16 k), col-half h. B-frag (32x32x16, round-0
  // proven): lane l holds W[C0+h*32+(l&31)][kq*256 + j*16 + (l>>5)*8 + 0..7].
  s16x8 Breg[32];
  {
    const float* wb = W + (size_t)(C0 + (lane & 31)) * NN
                        + kq*256 + (lane >> 5)*8;
    #pragma unroll
    for (int c = 0; c < 32; ++c) {
      const float* p = wb + (size_t)((c & 1)*32)*NN + (c >> 1)*16;
      float4 lo = *(const float4*)p;
      float4 hi = *(const float4*)(p + 4);
      union { u32x4 u; s16x8 s; } cv;
      cv.u = (u32x4){ pack2(lo.x, lo.y), pack2(lo.z, lo.w),
                      pack2(hi.x, hi.y), pack2(hi.z, hi.w) };
      Breg[c] = cv.s;
    }
  }

  __syncthreads();   // constants visible

  // ---- epilogue / S-build roles: row r_row (0..31), 4-col group cg (0..15)
  const int r_row = tid >> 4, cg = tid & 15;
  const int bg = g * 32 + r_row;
  // S A-frag slot (32x32): chunk = n/16; lane slot = (khalf<<5)|row; 8B by n&4
  const unsigned s_off = (unsigned)((bnx*4 + (cg>>2))*1024
                                    + ((((cg>>1)&1) << 5) + r_row)*16 + (cg&1)*8);

  // ---- build S_0 -> sbuf[g][0] ----
  {
    const float* s0p = state0 + (size_t)bg*NN + C0 + cg*4;
    float4 s4 = *(const float4*)s0p;
    float x0 = x[(size_t)bg*TT];
    float x1 = x[(size_t)(BB*TT) + (size_t)bg*TT];
    float sv[4] = {s4.x, s4.y, s4.z, s4.w};
    #pragma unroll
    for (int j = 0; j < 4; ++j) {
      int nl = cg*4 + j;
      sv[j] += cmask[nl] * (x0*cenc0[nl] + x1*cenc1[nl]);
    }
    u32x2 pk = { pack2(sv[0], sv[1]), pack2(sv[2], sv[3]) };
    store_b64_sys(sbufs + (size_t)g*NSB*SBUF_SZ + s_off, pk);
  }
  grid_barrier(flags, g*32, bnx, 1u, true);   // phase anchor: inv before step 0

  // ---- persistent time loop ----
  const int colc = lane & 31, rowb = 4 * (lane >> 5);
  float* mreg = (float*)(lds + LDS_R0) + (kq >> 1) * RSZW;
  unsigned pdpk = 0;

  for (int t = 0; t < TT; ++t) {
    const char* sb = sbufs + (size_t)(g*NSB + (t & (NSB-1))) * SBUF_SZ;
    char*       sn = sbufs + (size_t)(g*NSB + ((t+1) & (NSB-1))) * SBUF_SZ;

    // partials of step t-1: drains alongside the first load group (counted)
    if (t > 0 && cg == 0)
      store_u32_sys(&partials[((size_t)(t-1)*32 + bnx)*256 + bg], pdpk);

    // ---- A ring: 16 chunks (kq*16..), 8 slots, counted vmcnt (round-0) ----
    const char* ap = sb + (unsigned)(kq*16*1024) + (unsigned)(lane*16);
    s16x8 Ar[8];
    {
      const char* b0 = ap;
      LOAD_A(Ar[0], b0, 0);    LOAD_A(Ar[1], b0, 1024);
      LOAD_A(Ar[2], b0, 2048); LOAD_A(Ar[3], b0, 3072);
      const char* b1 = ap + 4096;
      LOAD_A(Ar[4], b1, 0);    LOAD_A(Ar[5], b1, 1024);
      LOAD_A(Ar[6], b1, 2048); LOAD_A(Ar[7], b1, 3072);
    }

    f32x16 acc0 = {0,0,0,0,0,0,0,0,0,0,0,0,0,0,0,0};
    f32x16 acc1 = {0,0,0,0,0,0,0,0,0,0,0,0,0,0,0,0};

    asm volatile("s_waitcnt vmcnt(4)"
      : "+v"(Ar[0]),"+v"(Ar[1]),"+v"(Ar[2]),"+v"(Ar[3]));
    #pragma unroll
    for (int i = 0; i < 4; ++i) {
      acc0 = __builtin_amdgcn_mfma_f32_32x32x16_bf16(Ar[i], Breg[i*2+0], acc0, 0,0,0);
      acc1 = __builtin_amdgcn_mfma_f32_32x32x16_bf16(Ar[i], Breg[i*2+1], acc1, 0,0,0);
    }
    {
      const char* b2 = ap + 8192;
      LOAD_A(Ar[0], b2, 0);    LOAD_A(Ar[1], b2, 1024);
      LOAD_A(Ar[2], b2, 2048); LOAD_A(Ar[3], b2, 3072);
    }
    asm volatile("s_waitcnt vmcnt(4)"
      : "+v"(Ar[4]),"+v"(Ar[5]),"+v"(Ar[6]),"+v"(Ar[7]));
    #pragma unroll
    for (int i = 0; i < 4; ++i) {
      acc0 = __builtin_amdgcn_mfma_f32_32x32x16_bf16(Ar[4+i], Breg[(4+i)*2+0], acc0, 0,0,0);
      acc1 = __builtin_amdgcn_mfma_f32_32x32x16_bf16(Ar[4+i], Breg[(4+i)*2+1], acc1, 0,0,0);
    }
    {
      const char* b3 = ap + 12288;
      LOAD_A(Ar[4], b3, 0);    LOAD_A(Ar[5], b3, 1024);
      LOAD_A(Ar[6], b3, 2048); LOAD_A(Ar[7], b3, 3072);
    }
    asm volatile("s_waitcnt vmcnt(4)"
      : "+v"(Ar[0]),"+v"(Ar[1]),"+v"(Ar[2]),"+v"(Ar[3]));
    #pragma unroll
    for (int i = 0; i < 4; ++i) {
      acc0 = __builtin_amdgcn_mfma_f32_32x32x16_bf16(Ar[i], Breg[(8+i)*2+0], acc0, 0,0,0);
      acc1 = __builtin_amdgcn_mfma_f32_32x32x16_bf16(Ar[i], Breg[(8+i)*2+1], acc1, 0,0,0);
    }
    asm volatile("s_waitcnt vmcnt(0)"
      : "+v"(Ar[4]),"+v"(Ar[5]),"+v"(Ar[6]),"+v"(Ar[7]));
    #pragma unroll
    for (int i = 0; i < 4; ++i) {
      acc0 = __builtin_amdgcn_mfma_f32_32x32x16_bf16(Ar[4+i], Breg[(12+i)*2+0], acc0, 0,0,0);
      acc1 = __builtin_amdgcn_mfma_f32_32x32x16_bf16(Ar[4+i], Breg[(12+i)*2+1], acc1, 0,0,0);
    }

    // ---- 2-phase race-free k-merge: 8 wave-partials -> 4 regions ----
    // C/D frag: col=lane&31, row=(r&3)+8*(r>>2)+4*(lane>>5)  (round-0 proven)
    if (kq & 1) {
      #pragma unroll
      for (int r = 0; r < 16; ++r) {
        int row = rowb + (r & 3) + 8*(r >> 2);
        mreg[row*MRGS + colc]      = acc0[r];
        mreg[row*MRGS + 32 + colc] = acc1[r];
      }
    }
    __syncthreads();
    if (!(kq & 1)) {
      #pragma unroll
      for (int r = 0; r < 16; ++r) {
        int row = rowb + (r & 3) + 8*(r >> 2);
        mreg[row*MRGS + colc]      += acc0[r];
        mreg[row*MRGS + 32 + colc] += acc1[r];
      }
    }
    __syncthreads();

    // ---- epilogue: sum 4 regions, sigmoid, next-S store, decoder ----
    {
      const float* m0 = (const float*)(lds + LDS_R0) + r_row*MRGS + cg*4;
      float4 q0 = *(const float4*)(m0);
      float4 q1 = *(const float4*)(m0 + RSZW);
      float4 q2 = *(const float4*)(m0 + 2*RSZW);
      float4 q3 = *(const float4*)(m0 + 3*RSZW);
      float x0n = 0.f, x1n = 0.f;
      if (t < TT - 1) {
        x0n = x[(size_t)bg*TT + t + 1];
        x1n = x[(size_t)(BB*TT) + (size_t)bg*TT + t + 1];
      }
      float pr[4] = {q0.x+q1.x+q2.x+q3.x, q0.y+q1.y+q2.y+q3.y,
                     q0.z+q1.z+q2.z+q3.z, q0.w+q1.w+q2.w+q3.w};
      float st[4];
      #pragma unroll
      for (int j = 0; j < 4; ++j) {
        int nl = cg*4 + j;
        float sg = 1.0f / (1.0f + __expf(-SLOPE * (pr[j] - cthr[nl])));
        st[j] = cmask[nl] * (cbias[nl] + sg);
      }
      if (t < TT - 1) {
        float sv[4];
        #pragma unroll
        for (int j = 0; j < 4; ++j) {
          int nl = cg*4 + j;
          sv[j] = st[j] + cmask[nl] * (x0n*cenc0[nl] + x1n*cenc1[nl]);
        }
        u32x2 pk = { pack2(sv[0], sv[1]), pack2(sv[2], sv[3]) };
        store_b64_sys(sn + s_off, pk);     // in flight during decoder VALU below
      }
      float d0 = 0.f, d1 = 0.f;
      #pragma unroll
      for (int j = 0; j < 4; ++j) {
        int nl = cg*4 + j;
        d0 += st[j] * cdec0[nl];
        d1 += st[j] * cdec1[nl];
      }
      d0 += __shfl_xor(d0, 1); d0 += __shfl_xor(d0, 2);
      d0 += __shfl_xor(d0, 4); d0 += __shfl_xor(d0, 8);
      d1 += __shfl_xor(d1, 1); d1 += __shfl_xor(d1, 2);
      d1 += __shfl_xor(d1, 4); d1 += __shfl_xor(d1, 8);
      pdpk = pack2(d0, d1);
    }

    if (t < TT - 1)
      grid_barrier(flags, g*32, bnx, (unsigned)(t + 2), ((t + 1) & (NSB-1)) == 0);
  }
  if (cg == 0)
    store_u32_sys(&partials[((size_t)(TT-1)*32 + bnx)*256 + bg], pdpk);
}

// out[c][b][t] = sum_bn unpack(partials[t][bn][b])
__global__ __launch_bounds__(256)
void reduce_out_kernel(const unsigned* __restrict__ partials, float* __restrict__ out) {
  const int t = blockIdx.x;
  const int b = threadIdx.x;
  const unsigned* p = partials + (size_t)t * 32 * 256 + b;
  float s0 = 0.f, s1 = 0.f;
  #pragma unroll
  for (int bn = 0; bn < 32; ++bn) {
    unsigned v = p[bn * 256];
    union { unsigned u; float f; } lo, hi;
    lo.u = v << 16; hi.u = v & 0xffff0000u;
    s0 += lo.f; s1 += hi.f;
  }
  out[(size_t)b * TT + t] = s0;
  out[(size_t)(BB * TT) + (size_t)b * TT + t] = s1;
}

extern "C" void kernel_launch(void* const* d_in, const int* in_sizes, int n_in,
                              void* d_out, int out_size, void* d_ws, size_t ws_size,
                              hipStream_t stream) {
  const float* x      = (const float*)d_in[0];
  const float* state0 = (const float*)d_in[1];
  const float* mask   = (const float*)d_in[2];
  const float* enc    = (const float*)d_in[3];
  const float* dec    = (const float*)d_in[4];
  const float* W      = (const float*)d_in[5];
  const float* bias   = (const float*)d_in[6];
  const float* thr    = (const float*)d_in[7];
  float* out = (float*)d_out;
  char*  ws  = (char*)d_ws;

  (void)hipMemsetAsync(ws, 0, 32768, stream);   // flags [8][32] x 128 B

  (void)hipFuncSetAttribute((const void*)mc_integrator_kernel,
                            hipFuncAttributeMaxDynamicSharedMemorySize, LDS_TOTAL);

  void* args[] = { (void*)&x, (void*)&state0, (void*)&mask, (void*)&enc, (void*)&dec,
                   (void*)&W, (void*)&bias, (void*)&thr, (void*)&ws };
  (void)hipLaunchCooperativeKernel((const void*)mc_integrator_kernel,
                                   dim3(NBLK), dim3(NTH), args, (unsigned)LDS_TOTAL, stream);

  const unsigned* partials = (const unsigned*)(ws + WS_PART);
  reduce_out_kernel<<<dim3(TT), dim3(256), 0, stream>>>(partials, out);
}

// Round 6
// 1255.373 us; speedup vs baseline: 1.2533x; 1.0561x over previous
//
#include <hip/hip_runtime.h>

// ManyChannelsIntegrator: C=2, B=256, T=256, N=2048
// R16 = R15 + fine-grained producer-flag consumption.
//  - 8 groups x 32 blocks; block = 32 rows x 64 n-cols. W in registers.
//  - Wave kq consumes k in [kq*256,+256) = S-chunks of producers kq*4..+3.
//    At step top each wave spins on ONLY its 4 producer flags, then loads.
//    Block-level merge syncthreads keeps group skew <= 1 step; NSB=8 slot
//    rotation + per-chunk ownership make skew-1 access disjoint.
//  - Full 32-member barrier + agent-acquire inv ONLY every 8th step
//    (round-0-proven cache-epoch hygiene). Producer side unchanged:
//    vmcnt(0) + syncthreads + system-scope flag store.
//  - x_{t+1} prefetched at step top (drained by the poll's implicit vmcnt0).

#define NN 2048
#define BB 256
#define TT 256
#define SLOPE 8.0f

#define NBLK 256
#define NTH  512
#define NSB  8      // S rotation depth; inv every NSB steps

// ---- LDS layout (bytes) ----
#define MRGS 68                            // merge region stride (f32 words)
#define RSZW (32*MRGS)                     // words per region (2176)
#define LDS_R0    0                        // 4 regions x 8704 B = 34816
#define LDS_CONST (4*RSZW*4)               // 7 x 64 f32 per-n constants
#define LDS_TOTAL (LDS_CONST + 7*64*4)     // 36608 B

// ---- ws layout (bytes) ----
#define WS_FLAGS 0                         // [8 g][32 member] x 128 B (memset 0)
#define WS_SBUF  32768                     // 8 groups x NSB x 128 KB = 8 MB
#define SBUF_SZ  131072
#define WS_PART  (32768 + 8*NSB*SBUF_SZ)   // [T][32 bn][256 b] u32

typedef short s16x8 __attribute__((ext_vector_type(8)));      // 8 bf16
typedef float f32x16 __attribute__((ext_vector_type(16)));
typedef unsigned u32x4 __attribute__((ext_vector_type(4)));
typedef unsigned u32x2 __attribute__((ext_vector_type(2)));

__device__ __forceinline__ unsigned f2bf1(float f) {
  union { float f; unsigned u; } v; v.f = f;
  return (v.u + 0x7fffu + ((v.u >> 16) & 1u)) >> 16;   // RNE
}
__device__ __forceinline__ unsigned pack2(float a, float b) {
  return f2bf1(a) | (f2bf1(b) << 16);
}

// System-scope write-through stores (never dirty L1/L2 -> inv safe).
__device__ __forceinline__ void store_b64_sys(void* p, u32x2 v) {
  asm volatile("global_store_dwordx2 %0, %1, off sc0 sc1" :: "v"(p), "v"(v) : "memory");
}
__device__ __forceinline__ void store_u32_sys(void* p, unsigned v) {
  asm volatile("global_store_dword %0, %1, off sc0 sc1" :: "v"(p), "v"(v) : "memory");
}

// A-load: plain -> L1/L2-cached (proven: L2 dedups the 32-way broadcast).
#define LOAD_A(dst, base, OFF) \
  asm volatile("global_load_dwordx4 %0, %1, off offset:" #OFF \
               : "=v"(dst) : "v"(base) : "memory")

// Full group barrier over 32 members (round-0 shape, line-padded flags).
__device__ __forceinline__ void grid_barrier(unsigned* flags, int gbase, int member,
                                             unsigned tval, bool do_inv) {
  asm volatile("s_waitcnt vmcnt(0)" ::: "memory");
  __syncthreads();
  const int tid = threadIdx.x;
  if (tid == 0)
    __hip_atomic_store(&flags[(gbase + member) * 32], tval,
                       __ATOMIC_RELAXED, __HIP_MEMORY_SCOPE_SYSTEM);
  if (tid < 64) {
    for (;;) {
      unsigned v = __hip_atomic_load(&flags[(gbase + (tid & 31)) * 32],
                                     __ATOMIC_RELAXED, __HIP_MEMORY_SCOPE_SYSTEM);
      if (__all(v >= tval)) break;
      __builtin_amdgcn_s_sleep(1);
    }
  }
  __syncthreads();
  if (do_inv) {
    if (tid < 64) __builtin_amdgcn_fence(__ATOMIC_ACQUIRE, "agent");
    __syncthreads();
  }
}

__global__ __launch_bounds__(NTH, 2)
void mc_integrator_kernel(const float* __restrict__ x, const float* __restrict__ state0,
                          const float* __restrict__ mask, const float* __restrict__ enc,
                          const float* __restrict__ dec, const float* __restrict__ W,
                          const float* __restrict__ bias, const float* __restrict__ thr,
                          char* __restrict__ ws)
{
  extern __shared__ char lds[];
  const int tid = threadIdx.x;
  const int blk = blockIdx.x;
  const int g   = blk & 7;          // group (XCD under m09 round-robin)
  const int bnx = blk >> 3;         // 0..31: 64-col n-strip
  const int C0  = bnx * 64;
  const int kq  = tid >> 6;         // wave = k-eighth (256 k)
  const int lane = tid & 63;

  unsigned* flags = (unsigned*)(ws + WS_FLAGS);   // member stride = 128 B
  char* sbufs = ws + WS_SBUF;
  unsigned* partials = (unsigned*)(ws + WS_PART);

  // ---- stage per-n constants (64 cols) ----
  float* cmask = (float*)(lds + LDS_CONST);
  float* cbias = cmask + 64; float* cthr  = cbias + 64;
  float* cenc0 = cthr  + 64; float* cenc1 = cenc0 + 64;
  float* cdec0 = cenc1 + 64; float* cdec1 = cdec0 + 64;
  if (tid < 64) {
    int n = C0 + tid;
    cmask[tid] = mask[n]; cbias[tid] = bias[n]; cthr[tid] = thr[n];
    cenc0[tid] = enc[n];  cenc1[tid] = enc[NN + n];
    cdec0[tid] = dec[n];  cdec1[tid] = dec[NN + n];
  }

  // ---- W -> registers. Wave kq owns k [kq*256,+256), all 64 cols.
  // Breg[j*2+h]: k-chunk j (16 k), col-half h. B-frag (32x32x16):
  // lane l holds W[C0+h*32+(l&31)][kq*256 + j*16 + (l>>5)*8 + 0..7].
  s16x8 Breg[32];
  {
    const float* wb = W + (size_t)(C0 + (lane & 31)) * NN
                        + kq*256 + (lane >> 5)*8;
    #pragma unroll
    for (int c = 0; c < 32; ++c) {
      const float* p = wb + (size_t)((c & 1)*32)*NN + (c >> 1)*16;
      float4 lo = *(const float4*)p;
      float4 hi = *(const float4*)(p + 4);
      union { u32x4 u; s16x8 s; } cv;
      cv.u = (u32x4){ pack2(lo.x, lo.y), pack2(lo.z, lo.w),
                      pack2(hi.x, hi.y), pack2(hi.z, hi.w) };
      Breg[c] = cv.s;
    }
  }

  __syncthreads();   // constants visible

  // ---- epilogue / S-build roles: row r_row (0..31), 4-col group cg (0..15)
  const int r_row = tid >> 4, cg = tid & 15;
  const int bg = g * 32 + r_row;
  // S A-frag slot (32x32): chunk = n/16; lane slot = (khalf<<5)|row; 8B by n&4
  const unsigned s_off = (unsigned)((bnx*4 + (cg>>2))*1024
                                    + ((((cg>>1)&1) << 5) + r_row)*16 + (cg&1)*8);

  // ---- build S_0 -> sbuf[g][0] ----
  {
    const float* s0p = state0 + (size_t)bg*NN + C0 + cg*4;
    float4 s4 = *(const float4*)s0p;
    float x0 = x[(size_t)bg*TT];
    float x1 = x[(size_t)(BB*TT) + (size_t)bg*TT];
    float sv[4] = {s4.x, s4.y, s4.z, s4.w};
    #pragma unroll
    for (int j = 0; j < 4; ++j) {
      int nl = cg*4 + j;
      sv[j] += cmask[nl] * (x0*cenc0[nl] + x1*cenc1[nl]);
    }
    u32x2 pk = { pack2(sv[0], sv[1]), pack2(sv[2], sv[3]) };
    store_b64_sys(sbufs + (size_t)g*NSB*SBUF_SZ + s_off, pk);
  }
  grid_barrier(flags, g*32, bnx, 1u, true);   // phase anchor: inv before step 0

  // ---- persistent time loop ----
  const int colc = lane & 31, rowb = 4 * (lane >> 5);
  float* mreg = (float*)(lds + LDS_R0) + (kq >> 1) * RSZW;
  unsigned pdpk = 0;

  for (int t = 0; t < TT; ++t) {
    const char* sb = sbufs + (size_t)(g*NSB + (t & (NSB-1))) * SBUF_SZ;
    char*       sn = sbufs + (size_t)(g*NSB + ((t+1) & (NSB-1))) * SBUF_SZ;

    // partials of step t-1 + x_{t+1} prefetch: issued before the poll; the
    // poll's implicit vmcnt(0) (atomic-load use) drains them for free.
    if (t > 0 && cg == 0)
      store_u32_sys(&partials[((size_t)(t-1)*32 + bnx)*256 + bg], pdpk);
    float x0n = 0.f, x1n = 0.f;
    if (t < TT - 1) {
      x0n = x[(size_t)bg*TT + t + 1];
      x1n = x[(size_t)(BB*TT) + (size_t)bg*TT + t + 1];
    }

    // ---- per-wave producer poll: wave kq needs members kq*4..+3 at >= t+1.
    // Skipped right after a full barrier (t % 8 == 0): already guaranteed.
    if (t & (NSB-1)) {
      if (lane < 4) {
        const unsigned tvc = (unsigned)(t + 1);
        for (;;) {
          unsigned v = __hip_atomic_load(&flags[(g*32 + kq*4 + lane) * 32],
                                         __ATOMIC_RELAXED, __HIP_MEMORY_SCOPE_SYSTEM);
          if (__all(v >= tvc)) break;
          __builtin_amdgcn_s_sleep(1);
        }
      }
    }

    // ---- A ring: 16 chunks (kq*16..), 8 slots, counted vmcnt ----
    const char* ap = sb + (unsigned)(kq*16*1024) + (unsigned)(lane*16);
    s16x8 Ar[8];
    {
      const char* b0 = ap;
      LOAD_A(Ar[0], b0, 0);    LOAD_A(Ar[1], b0, 1024);
      LOAD_A(Ar[2], b0, 2048); LOAD_A(Ar[3], b0, 3072);
      const char* b1 = ap + 4096;
      LOAD_A(Ar[4], b1, 0);    LOAD_A(Ar[5], b1, 1024);
      LOAD_A(Ar[6], b1, 2048); LOAD_A(Ar[7], b1, 3072);
    }

    f32x16 acc0 = {0,0,0,0,0,0,0,0,0,0,0,0,0,0,0,0};
    f32x16 acc1 = {0,0,0,0,0,0,0,0,0,0,0,0,0,0,0,0};

    asm volatile("s_waitcnt vmcnt(4)"
      : "+v"(Ar[0]),"+v"(Ar[1]),"+v"(Ar[2]),"+v"(Ar[3]));
    #pragma unroll
    for (int i = 0; i < 4; ++i) {
      acc0 = __builtin_amdgcn_mfma_f32_32x32x16_bf16(Ar[i], Breg[i*2+0], acc0, 0,0,0);
      acc1 = __builtin_amdgcn_mfma_f32_32x32x16_bf16(Ar[i], Breg[i*2+1], acc1, 0,0,0);
    }
    {
      const char* b2 = ap + 8192;
      LOAD_A(Ar[0], b2, 0);    LOAD_A(Ar[1], b2, 1024);
      LOAD_A(Ar[2], b2, 2048); LOAD_A(Ar[3], b2, 3072);
    }
    asm volatile("s_waitcnt vmcnt(4)"
      : "+v"(Ar[4]),"+v"(Ar[5]),"+v"(Ar[6]),"+v"(Ar[7]));
    #pragma unroll
    for (int i = 0; i < 4; ++i) {
      acc0 = __builtin_amdgcn_mfma_f32_32x32x16_bf16(Ar[4+i], Breg[(4+i)*2+0], acc0, 0,0,0);
      acc1 = __builtin_amdgcn_mfma_f32_32x32x16_bf16(Ar[4+i], Breg[(4+i)*2+1], acc1, 0,0,0);
    }
    {
      const char* b3 = ap + 12288;
      LOAD_A(Ar[4], b3, 0);    LOAD_A(Ar[5], b3, 1024);
      LOAD_A(Ar[6], b3, 2048); LOAD_A(Ar[7], b3, 3072);
    }
    asm volatile("s_waitcnt vmcnt(4)"
      : "+v"(Ar[0]),"+v"(Ar[1]),"+v"(Ar[2]),"+v"(Ar[3]));
    #pragma unroll
    for (int i = 0; i < 4; ++i) {
      acc0 = __builtin_amdgcn_mfma_f32_32x32x16_bf16(Ar[i], Breg[(8+i)*2+0], acc0, 0,0,0);
      acc1 = __builtin_amdgcn_mfma_f32_32x32x16_bf16(Ar[i], Breg[(8+i)*2+1], acc1, 0,0,0);
    }
    asm volatile("s_waitcnt vmcnt(0)"
      : "+v"(Ar[4]),"+v"(Ar[5]),"+v"(Ar[6]),"+v"(Ar[7]));
    #pragma unroll
    for (int i = 0; i < 4; ++i) {
      acc0 = __builtin_amdgcn_mfma_f32_32x32x16_bf16(Ar[4+i], Breg[(12+i)*2+0], acc0, 0,0,0);
      acc1 = __builtin_amdgcn_mfma_f32_32x32x16_bf16(Ar[4+i], Breg[(12+i)*2+1], acc1, 0,0,0);
    }

    // ---- 2-phase race-free k-merge: 8 wave-partials -> 4 regions ----
    // C/D frag: col=lane&31, row=(r&3)+8*(r>>2)+4*(lane>>5)
    if (kq & 1) {
      #pragma unroll
      for (int r = 0; r < 16; ++r) {
        int row = rowb + (r & 3) + 8*(r >> 2);
        mreg[row*MRGS + colc]      = acc0[r];
        mreg[row*MRGS + 32 + colc] = acc1[r];
      }
    }
    __syncthreads();
    if (!(kq & 1)) {
      #pragma unroll
      for (int r = 0; r < 16; ++r) {
        int row = rowb + (r & 3) + 8*(r >> 2);
        mreg[row*MRGS + colc]      += acc0[r];
        mreg[row*MRGS + 32 + colc] += acc1[r];
      }
    }
    __syncthreads();

    // ---- epilogue: sum 4 regions, sigmoid, next-S store, decoder ----
    {
      const float* m0 = (const float*)(lds + LDS_R0) + r_row*MRGS + cg*4;
      float4 q0 = *(const float4*)(m0);
      float4 q1 = *(const float4*)(m0 + RSZW);
      float4 q2 = *(const float4*)(m0 + 2*RSZW);
      float4 q3 = *(const float4*)(m0 + 3*RSZW);
      float pr[4] = {q0.x+q1.x+q2.x+q3.x, q0.y+q1.y+q2.y+q3.y,
                     q0.z+q1.z+q2.z+q3.z, q0.w+q1.w+q2.w+q3.w};
      float st[4];
      #pragma unroll
      for (int j = 0; j < 4; ++j) {
        int nl = cg*4 + j;
        float sg = 1.0f / (1.0f + __expf(-SLOPE * (pr[j] - cthr[nl])));
        st[j] = cmask[nl] * (cbias[nl] + sg);
      }
      if (t < TT - 1) {
        float sv[4];
        #pragma unroll
        for (int j = 0; j < 4; ++j) {
          int nl = cg*4 + j;
          sv[j] = st[j] + cmask[nl] * (x0n*cenc0[nl] + x1n*cenc1[nl]);
        }
        u32x2 pk = { pack2(sv[0], sv[1]), pack2(sv[2], sv[3]) };
        store_b64_sys(sn + s_off, pk);     // in flight during decoder VALU below
      }
      float d0 = 0.f, d1 = 0.f;
      #pragma unroll
      for (int j = 0; j < 4; ++j) {
        int nl = cg*4 + j;
        d0 += st[j] * cdec0[nl];
        d1 += st[j] * cdec1[nl];
      }
      d0 += __shfl_xor(d0, 1); d0 += __shfl_xor(d0, 2);
      d0 += __shfl_xor(d0, 4); d0 += __shfl_xor(d0, 8);
      d1 += __shfl_xor(d1, 1); d1 += __shfl_xor(d1, 2);
      d1 += __shfl_xor(d1, 4); d1 += __shfl_xor(d1, 8);
      pdpk = pack2(d0, d1);
    }

    // ---- step end: full barrier+inv on epoch boundary; else producer-only.
    if (t < TT - 1) {
      if (((t + 1) & (NSB-1)) == 0) {
        grid_barrier(flags, g*32, bnx, (unsigned)(t + 2), true);
      } else {
        asm volatile("s_waitcnt vmcnt(0)" ::: "memory");   // S stores drained
        __syncthreads();                                   // all waves' stores
        if (tid == 0)
          __hip_atomic_store(&flags[(g*32 + bnx) * 32], (unsigned)(t + 2),
                             __ATOMIC_RELAXED, __HIP_MEMORY_SCOPE_SYSTEM);
      }
    }
  }
  if (cg == 0)
    store_u32_sys(&partials[((size_t)(TT-1)*32 + bnx)*256 + bg], pdpk);
}

// out[c][b][t] = sum_bn unpack(partials[t][bn][b])
__global__ __launch_bounds__(256)
void reduce_out_kernel(const unsigned* __restrict__ partials, float* __restrict__ out) {
  const int t = blockIdx.x;
  const int b = threadIdx.x;
  const unsigned* p = partials + (size_t)t * 32 * 256 + b;
  float s0 = 0.f, s1 = 0.f;
  #pragma unroll
  for (int bn = 0; bn < 32; ++bn) {
    unsigned v = p[bn * 256];
    union { unsigned u; float f; } lo, hi;
    lo.u = v << 16; hi.u = v & 0xffff0000u;
    s0 += lo.f; s1 += hi.f;
  }
  out[(size_t)b * TT + t] = s0;
  out[(size_t)(BB * TT) + (size_t)b * TT + t] = s1;
}

extern "C" void kernel_launch(void* const* d_in, const int* in_sizes, int n_in,
                              void* d_out, int out_size, void* d_ws, size_t ws_size,
                              hipStream_t stream) {
  const float* x      = (const float*)d_in[0];
  const float* state0 = (const float*)d_in[1];
  const float* mask   = (const float*)d_in[2];
  const float* enc    = (const float*)d_in[3];
  const float* dec    = (const float*)d_in[4];
  const float* W      = (const float*)d_in[5];
  const float* bias   = (const float*)d_in[6];
  const float* thr    = (const float*)d_in[7];
  float* out = (float*)d_out;
  char*  ws  = (char*)d_ws;

  (void)hipMemsetAsync(ws, 0, 32768, stream);   // flags [8][32] x 128 B

  (void)hipFuncSetAttribute((const void*)mc_integrator_kernel,
                            hipFuncAttributeMaxDynamicSharedMemorySize, LDS_TOTAL);

  void* args[] = { (void*)&x, (void*)&state0, (void*)&mask, (void*)&enc, (void*)&dec,
                   (void*)&W, (void*)&bias, (void*)&thr, (void*)&ws };
  (void)hipLaunchCooperativeKernel((const void*)mc_integrator_kernel,
                                   dim3(NBLK), dim3(NTH), args, (unsigned)LDS_TOTAL, stream);

  const unsigned* partials = (const unsigned*)(ws + WS_PART);
  reduce_out_kernel<<<dim3(TT), dim3(256), 0, stream>>>(partials, out);
}

// Round 7
// 1243.042 us; speedup vs baseline: 1.2658x; 1.0099x over previous
//
#include <hip/hip_runtime.h>

// ManyChannelsIntegrator: C=2, B=256, T=256, N=2048
// R17 = R16 + XCD-local FAST data path (proven-construct-only):
//  - flags/polls: __hip_atomic SYSTEM scope ALWAYS (R0-proven; no sc0 spins).
//  - co-XCD detection: s_getreg(HW_REG_XCC_ID) (learn_hip m09-proven on this
//    HW). FAST iff every group's 32 members are uniform AND >=2 groups differ.
//  - FAST: S stores plain (dirty own-XCD L2), A-loads sc0 (L1-bypass, L2-read),
//    NO fences (write-before-read within one L2; sc0 kills L1 staleness).
//  - SLOW: R16 verbatim (sc0 sc1 write-through + epoch inv) - proven fallback.
//  - Anti-dep without barriers: each block's 8 waves collectively poll all 32
//    producers every step => global skew <= 1 step << NSB=8 slot depth.

#define NN 2048
#define BB 256
#define TT 256
#define SLOPE 8.0f

#define NBLK 256
#define NTH  512
#define NSB  8      // S rotation depth

// ---- LDS layout (bytes) ----
#define MRGS 68                            // merge region stride (f32 words)
#define RSZW (32*MRGS)                     // words per region (2176)
#define LDS_R0    0                        // 4 regions x 8704 B = 34816
#define LDS_CONST (4*RSZW*4)               // 7 x 64 f32 per-n constants
#define LDS_MISC  (LDS_CONST + 7*64*4)     // fast-flag broadcast word
#define LDS_TOTAL (LDS_MISC + 16)          // 36624 B

// ---- ws layout (bytes) ----
#define WS_FLAGS 0                         // [8 g][32 member] x 128 B (memset 0)
#define WS_XCC   32768                     // [8][32] u32 XCC ids
#define WS_SBUF  65536                     // 8 groups x NSB x 128 KB = 8 MB
#define SBUF_SZ  131072
#define WS_PART  (65536 + 8*NSB*SBUF_SZ)   // [T][32 bn][256 b] u32

typedef short s16x8 __attribute__((ext_vector_type(8)));      // 8 bf16
typedef float f32x16 __attribute__((ext_vector_type(16)));
typedef unsigned u32x4 __attribute__((ext_vector_type(4)));
typedef unsigned u32x2 __attribute__((ext_vector_type(2)));

__device__ __forceinline__ unsigned f2bf1(float f) {
  union { float f; unsigned u; } v; v.f = f;
  return (v.u + 0x7fffu + ((v.u >> 16) & 1u)) >> 16;   // RNE
}
__device__ __forceinline__ unsigned pack2(float a, float b) {
  return f2bf1(a) | (f2bf1(b) << 16);
}

// System-scope write-through stores (never dirty L1/L2 -> inv safe).
__device__ __forceinline__ void store_b64_sys(void* p, u32x2 v) {
  asm volatile("global_store_dwordx2 %0, %1, off sc0 sc1" :: "v"(p), "v"(v) : "memory");
}
__device__ __forceinline__ void store_u32_sys(void* p, unsigned v) {
  asm volatile("global_store_dword %0, %1, off sc0 sc1" :: "v"(p), "v"(v) : "memory");
}

// A-load. FAST: sc0 = L1-bypass, read own-XCD L2 (fresh dirty lines).
// SLOW: plain cached (R16-proven; L2 holds write-through copies).
template<bool FAST>
__device__ __forceinline__ void load_a16(s16x8& d, const char* a) {
  if constexpr (FAST)
    asm volatile("global_load_dwordx4 %0, %1, off sc0" : "=v"(d) : "v"(a) : "memory");
  else
    asm volatile("global_load_dwordx4 %0, %1, off"     : "=v"(d) : "v"(a) : "memory");
}

// Full group barrier over 32 members (R0 shape, line-padded flags).
__device__ __forceinline__ void grid_barrier(unsigned* flags, int gbase, int member,
                                             unsigned tval, bool do_inv) {
  asm volatile("s_waitcnt vmcnt(0)" ::: "memory");
  __syncthreads();
  const int tid = threadIdx.x;
  if (tid == 0)
    __hip_atomic_store(&flags[(gbase + member) * 32], tval,
                       __ATOMIC_RELAXED, __HIP_MEMORY_SCOPE_SYSTEM);
  if (tid < 64) {
    for (;;) {
      unsigned v = __hip_atomic_load(&flags[(gbase + (tid & 31)) * 32],
                                     __ATOMIC_RELAXED, __HIP_MEMORY_SCOPE_SYSTEM);
      if (__all(v >= tval)) break;
      __builtin_amdgcn_s_sleep(1);
    }
  }
  __syncthreads();
  if (do_inv) {
    if (tid < 64) __builtin_amdgcn_fence(__ATOMIC_ACQUIRE, "agent");
    __syncthreads();
  }
}

// Time loop. Flag protocol: after prologue flags==2 (S_0 ready). End of step t
// publishes t+3 (S_{t+1} ready). Poll at step t waits for >= t+2.
template<bool FAST>
__device__ __forceinline__ void time_loop(const float* __restrict__ x,
    unsigned* flags, char* sbufs, unsigned* partials, char* lds,
    const s16x8 (&Breg)[32], int g, int bnx)
{
  const int tid  = threadIdx.x;
  const int kq   = tid >> 6;              // wave = k-eighth (256 k)
  const int lane = tid & 63;
  const int colc = lane & 31, rowb = 4 * (lane >> 5);
  const int r_row = tid >> 4, cg = tid & 15;   // epilogue roles
  const int bg = g * 32 + r_row;
  const unsigned s_off = (unsigned)((bnx*4 + (cg>>2))*1024
                                    + ((((cg>>1)&1) << 5) + r_row)*16 + (cg&1)*8);
  float* mreg = (float*)(lds + LDS_R0) + (kq >> 1) * RSZW;
  const float* cmask = (const float*)(lds + LDS_CONST);
  const float* cbias = cmask + 64; const float* cthr  = cbias + 64;
  const float* cenc0 = cthr  + 64; const float* cenc1 = cenc0 + 64;
  const float* cdec0 = cenc1 + 64; const float* cdec1 = cdec0 + 64;

  unsigned pdpk = 0;

  for (int t = 0; t < TT; ++t) {
    const char* sb = sbufs + (size_t)(g*NSB + (t & (NSB-1))) * SBUF_SZ;
    char*       sn = sbufs + (size_t)(g*NSB + ((t+1) & (NSB-1))) * SBUF_SZ;

    // partials of step t-1 + x_{t+1} prefetch: drained by the poll/waitcnts.
    if (t > 0 && cg == 0)
      store_u32_sys(&partials[((size_t)(t-1)*32 + bnx)*256 + bg], pdpk);
    float x0n = 0.f, x1n = 0.f;
    if (t < TT - 1) {
      x0n = x[(size_t)bg*TT + t + 1];
      x1n = x[(size_t)(BB*TT) + (size_t)bg*TT + t + 1];
    }

    // ---- per-wave producer poll: wave kq needs members kq*4..+3 >= t+2.
    // FAST: every step t>0. SLOW: skip right after an epoch barrier.
    const bool need_poll = FAST ? (t > 0) : ((t & (NSB-1)) != 0);
    if (need_poll) {
      if (lane < 4) {
        const unsigned tvc = (unsigned)(t + 2);
        for (;;) {
          unsigned v = __hip_atomic_load(&flags[(g*32 + kq*4 + lane) * 32],
                                         __ATOMIC_RELAXED, __HIP_MEMORY_SCOPE_SYSTEM);
          if (__all(v >= tvc)) break;
          __builtin_amdgcn_s_sleep(1);
        }
      }
    }

    // ---- A ring: 16 chunks (kq*16..), 8 slots, counted vmcnt ----
    const char* ap = sb + (unsigned)(kq*16*1024) + (unsigned)(lane*16);
    s16x8 Ar[8];
    #pragma unroll
    for (int i = 0; i < 8; ++i) load_a16<FAST>(Ar[i], ap + i*1024);

    f32x16 acc0 = {0,0,0,0,0,0,0,0,0,0,0,0,0,0,0,0};
    f32x16 acc1 = {0,0,0,0,0,0,0,0,0,0,0,0,0,0,0,0};

    asm volatile("s_waitcnt vmcnt(4)"
      : "+v"(Ar[0]),"+v"(Ar[1]),"+v"(Ar[2]),"+v"(Ar[3]));
    #pragma unroll
    for (int i = 0; i < 4; ++i) {
      acc0 = __builtin_amdgcn_mfma_f32_32x32x16_bf16(Ar[i], Breg[i*2+0], acc0, 0,0,0);
      acc1 = __builtin_amdgcn_mfma_f32_32x32x16_bf16(Ar[i], Breg[i*2+1], acc1, 0,0,0);
    }
    #pragma unroll
    for (int i = 0; i < 4; ++i) load_a16<FAST>(Ar[i], ap + (8+i)*1024);

    asm volatile("s_waitcnt vmcnt(4)"
      : "+v"(Ar[4]),"+v"(Ar[5]),"+v"(Ar[6]),"+v"(Ar[7]));
    #pragma unroll
    for (int i = 0; i < 4; ++i) {
      acc0 = __builtin_amdgcn_mfma_f32_32x32x16_bf16(Ar[4+i], Breg[(4+i)*2+0], acc0, 0,0,0);
      acc1 = __builtin_amdgcn_mfma_f32_32x32x16_bf16(Ar[4+i], Breg[(4+i)*2+1], acc1, 0,0,0);
    }
    #pragma unroll
    for (int i = 0; i < 4; ++i) load_a16<FAST>(Ar[4+i], ap + (12+i)*1024);

    asm volatile("s_waitcnt vmcnt(4)"
      : "+v"(Ar[0]),"+v"(Ar[1]),"+v"(Ar[2]),"+v"(Ar[3]));
    #pragma unroll
    for (int i = 0; i < 4; ++i) {
      acc0 = __builtin_amdgcn_mfma_f32_32x32x16_bf16(Ar[i], Breg[(8+i)*2+0], acc0, 0,0,0);
      acc1 = __builtin_amdgcn_mfma_f32_32x32x16_bf16(Ar[i], Breg[(8+i)*2+1], acc1, 0,0,0);
    }
    asm volatile("s_waitcnt vmcnt(0)"
      : "+v"(Ar[4]),"+v"(Ar[5]),"+v"(Ar[6]),"+v"(Ar[7]));
    #pragma unroll
    for (int i = 0; i < 4; ++i) {
      acc0 = __builtin_amdgcn_mfma_f32_32x32x16_bf16(Ar[4+i], Breg[(12+i)*2+0], acc0, 0,0,0);
      acc1 = __builtin_amdgcn_mfma_f32_32x32x16_bf16(Ar[4+i], Breg[(12+i)*2+1], acc1, 0,0,0);
    }

    // ---- 2-phase race-free k-merge: 8 wave-partials -> 4 regions ----
    if (kq & 1) {
      #pragma unroll
      for (int r = 0; r < 16; ++r) {
        int row = rowb + (r & 3) + 8*(r >> 2);
        mreg[row*MRGS + colc]      = acc0[r];
        mreg[row*MRGS + 32 + colc] = acc1[r];
      }
    }
    __syncthreads();
    if (!(kq & 1)) {
      #pragma unroll
      for (int r = 0; r < 16; ++r) {
        int row = rowb + (r & 3) + 8*(r >> 2);
        mreg[row*MRGS + colc]      += acc0[r];
        mreg[row*MRGS + 32 + colc] += acc1[r];
      }
    }
    __syncthreads();

    // ---- epilogue: sum 4 regions, sigmoid, next-S store, decoder ----
    {
      const float* m0 = (const float*)(lds + LDS_R0) + r_row*MRGS + cg*4;
      float4 q0 = *(const float4*)(m0);
      float4 q1 = *(const float4*)(m0 + RSZW);
      float4 q2 = *(const float4*)(m0 + 2*RSZW);
      float4 q3 = *(const float4*)(m0 + 3*RSZW);
      float pr[4] = {q0.x+q1.x+q2.x+q3.x, q0.y+q1.y+q2.y+q3.y,
                     q0.z+q1.z+q2.z+q3.z, q0.w+q1.w+q2.w+q3.w};
      float st[4];
      #pragma unroll
      for (int j = 0; j < 4; ++j) {
        int nl = cg*4 + j;
        float sg = 1.0f / (1.0f + __expf(-SLOPE * (pr[j] - cthr[nl])));
        st[j] = cmask[nl] * (cbias[nl] + sg);
      }
      if (t < TT - 1) {
        float sv[4];
        #pragma unroll
        for (int j = 0; j < 4; ++j) {
          int nl = cg*4 + j;
          sv[j] = st[j] + cmask[nl] * (x0n*cenc0[nl] + x1n*cenc1[nl]);
        }
        u32x2 pk = { pack2(sv[0], sv[1]), pack2(sv[2], sv[3]) };
        if constexpr (FAST) *(u32x2*)(sn + s_off) = pk;   // dirty own-XCD L2
        else                store_b64_sys(sn + s_off, pk);
      }
      float d0 = 0.f, d1 = 0.f;
      #pragma unroll
      for (int j = 0; j < 4; ++j) {
        int nl = cg*4 + j;
        d0 += st[j] * cdec0[nl];
        d1 += st[j] * cdec1[nl];
      }
      d0 += __shfl_xor(d0, 1); d0 += __shfl_xor(d0, 2);
      d0 += __shfl_xor(d0, 4); d0 += __shfl_xor(d0, 8);
      d1 += __shfl_xor(d1, 1); d1 += __shfl_xor(d1, 2);
      d1 += __shfl_xor(d1, 4); d1 += __shfl_xor(d1, 8);
      pdpk = pack2(d0, d1);
    }

    // ---- step end: publish S_{t+1} (flag = t+3) ----
    if (t < TT - 1) {
      if (!FAST && ((t + 1) & (NSB-1)) == 0) {
        grid_barrier(flags, g*32, bnx, (unsigned)(t + 3), true);  // epoch + inv
      } else {
        asm volatile("s_waitcnt vmcnt(0)" ::: "memory");   // S stores acked
        __syncthreads();                                   // all waves' stores
        if (tid == 0)
          __hip_atomic_store(&flags[(g*32 + bnx) * 32], (unsigned)(t + 3),
                             __ATOMIC_RELAXED, __HIP_MEMORY_SCOPE_SYSTEM);
      }
    }
  }
  if (cg == 0)
    store_u32_sys(&partials[((size_t)(TT-1)*32 + bnx)*256 + bg], pdpk);
}

__global__ __launch_bounds__(NTH, 2)
void mc_integrator_kernel(const float* __restrict__ x, const float* __restrict__ state0,
                          const float* __restrict__ mask, const float* __restrict__ enc,
                          const float* __restrict__ dec, const float* __restrict__ W,
                          const float* __restrict__ bias, const float* __restrict__ thr,
                          char* __restrict__ ws)
{
  extern __shared__ char lds[];
  const int tid = threadIdx.x;
  const int blk = blockIdx.x;
  const int g   = blk & 7;          // group (XCD under m09 round-robin)
  const int bnx = blk >> 3;         // 0..31: 64-col n-strip
  const int C0  = bnx * 64;
  const int kq  = tid >> 6, lane = tid & 63;

  unsigned* flags = (unsigned*)(ws + WS_FLAGS);   // member stride = 128 B
  unsigned* xccs  = (unsigned*)(ws + WS_XCC);
  char* sbufs = ws + WS_SBUF;
  unsigned* partials = (unsigned*)(ws + WS_PART);

  // ---- stage per-n constants (64 cols) ----
  float* cmask = (float*)(lds + LDS_CONST);
  float* cbias = cmask + 64; float* cthr  = cbias + 64;
  float* cenc0 = cthr  + 64; float* cenc1 = cenc0 + 64;
  float* cdec0 = cenc1 + 64; float* cdec1 = cdec0 + 64;
  if (tid < 64) {
    int n = C0 + tid;
    cmask[tid] = mask[n]; cbias[tid] = bias[n]; cthr[tid] = thr[n];
    cenc0[tid] = enc[n];  cenc1[tid] = enc[NN + n];
    cdec0[tid] = dec[n];  cdec1[tid] = dec[NN + n];
  }

  // ---- W -> registers (B-frag 32x32x16, proven layout) ----
  s16x8 Breg[32];
  {
    const float* wb = W + (size_t)(C0 + (lane & 31)) * NN
                        + kq*256 + (lane >> 5)*8;
    #pragma unroll
    for (int c = 0; c < 32; ++c) {
      const float* p = wb + (size_t)((c & 1)*32)*NN + (c >> 1)*16;
      float4 lo = *(const float4*)p;
      float4 hi = *(const float4*)(p + 4);
      union { u32x4 u; s16x8 s; } cv;
      cv.u = (u32x4){ pack2(lo.x, lo.y), pack2(lo.z, lo.w),
                      pack2(hi.x, hi.y), pack2(hi.z, hi.w) };
      Breg[c] = cv.s;
    }
  }

  // ---- publish XCC id (m09-proven hwreg read; system store) ----
  unsigned myxcc;
  asm volatile("s_getreg_b32 %0, hwreg(HW_REG_XCC_ID)" : "=s"(myxcc));
  if (tid == 0) store_u32_sys(&xccs[g*32 + bnx], myxcc);

  __syncthreads();   // constants visible
  grid_barrier(flags, g*32, bnx, 1u, true);   // xccs published; caches clean

  // ---- GLOBAL co-XCD decision (uniform across all blocks) ----
  if (tid < 32) {
    int allco = 1, distinct = 0;
    unsigned lead0 = 0;
    #pragma unroll
    for (int j = 0; j < 8; ++j) {
      unsigned v = __hip_atomic_load(&xccs[j*32 + tid],
                                     __ATOMIC_RELAXED, __HIP_MEMORY_SCOPE_SYSTEM);
      unsigned u = (unsigned)__shfl((int)v, 0);
      if (!__all(v == u)) allco = 0;
      if (j == 0) lead0 = u; else if (u != lead0) distinct = 1;
    }
    if (tid == 0) *(volatile int*)(lds + LDS_MISC) = (allco && distinct) ? 1 : 0;
  }
  __syncthreads();
  const bool fast = (*(volatile int*)(lds + LDS_MISC)) != 0;

  // ---- build S_0 -> sbuf[g][0] (mode-appropriate stores) ----
  {
    const int r_row = tid >> 4, cg = tid & 15;
    const int bg = g*32 + r_row;
    const unsigned s_off = (unsigned)((bnx*4 + (cg>>2))*1024
                                      + ((((cg>>1)&1) << 5) + r_row)*16 + (cg&1)*8);
    const float* s0p = state0 + (size_t)bg*NN + C0 + cg*4;
    float4 s4 = *(const float4*)s0p;
    float x0 = x[(size_t)bg*TT];
    float x1 = x[(size_t)(BB*TT) + (size_t)bg*TT];
    float sv[4] = {s4.x, s4.y, s4.z, s4.w};
    #pragma unroll
    for (int j = 0; j < 4; ++j) {
      int nl = cg*4 + j;
      sv[j] += cmask[nl] * (x0*cenc0[nl] + x1*cenc1[nl]);
    }
    u32x2 pk = { pack2(sv[0], sv[1]), pack2(sv[2], sv[3]) };
    char* dst = sbufs + (size_t)g*NSB*SBUF_SZ + s_off;
    if (fast) *(u32x2*)dst = pk;     // plain: updates own-XCD L2 in place
    else      store_b64_sys(dst, pk);
  }
  grid_barrier(flags, g*32, bnx, 2u, !fast);   // S_0 ready; inv only in SLOW

  if (fast) time_loop<true >(x, flags, sbufs, partials, lds, Breg, g, bnx);
  else      time_loop<false>(x, flags, sbufs, partials, lds, Breg, g, bnx);
}

// out[c][b][t] = sum_bn unpack(partials[t][bn][b])
__global__ __launch_bounds__(256)
void reduce_out_kernel(const unsigned* __restrict__ partials, float* __restrict__ out) {
  const int t = blockIdx.x;
  const int b = threadIdx.x;
  const unsigned* p = partials + (size_t)t * 32 * 256 + b;
  float s0 = 0.f, s1 = 0.f;
  #pragma unroll
  for (int bn = 0; bn < 32; ++bn) {
    unsigned v = p[bn * 256];
    union { unsigned u; float f; } lo, hi;
    lo.u = v << 16; hi.u = v & 0xffff0000u;
    s0 += lo.f; s1 += hi.f;
  }
  out[(size_t)b * TT + t] = s0;
  out[(size_t)(BB * TT) + (size_t)b * TT + t] = s1;
}

extern "C" void kernel_launch(void* const* d_in, const int* in_sizes, int n_in,
                              void* d_out, int out_size, void* d_ws, size_t ws_size,
                              hipStream_t stream) {
  const float* x      = (const float*)d_in[0];
  const float* state0 = (const float*)d_in[1];
  const float* mask   = (const float*)d_in[2];
  const float* enc    = (const float*)d_in[3];
  const float* dec    = (const float*)d_in[4];
  const float* W      = (const float*)d_in[5];
  const float* bias   = (const float*)d_in[6];
  const float* thr    = (const float*)d_in[7];
  float* out = (float*)d_out;
  char*  ws  = (char*)d_ws;

  (void)hipMemsetAsync(ws, 0, 32768, stream);   // flags [8][32] x 128 B

  (void)hipFuncSetAttribute((const void*)mc_integrator_kernel,
                            hipFuncAttributeMaxDynamicSharedMemorySize, LDS_TOTAL);

  void* args[] = { (void*)&x, (void*)&state0, (void*)&mask, (void*)&enc, (void*)&dec,
                   (void*)&W, (void*)&bias, (void*)&thr, (void*)&ws };
  (void)hipLaunchCooperativeKernel((const void*)mc_integrator_kernel,
                                   dim3(NBLK), dim3(NTH), args, (unsigned)LDS_TOTAL, stream);

  const unsigned* partials = (const unsigned*)(ws + WS_PART);
  reduce_out_kernel<<<dim3(TT), dim3(256), 0, stream>>>(partials, out);
}